// Round 7
// baseline (252.534 us; speedup 1.0000x reference)
//
#include <hip/hip_runtime.h>

#define BB 4
#define CC 32
#define HH 480
#define WW 640
#define HWv (HH*WW)

// ---------------------------------------------------------------------------
// Kernel 1: 3x3 conv (32->8) + bias + affinity normalization, fused.
// (Exact R2 structure — best measured: 115.5 us.)
// Each thread computes 8 consecutive pixels along x.
// Output: K [B][9][H][W], K[0] = 1 - sum(a), K[1..8] = a_k = aff_k / sum|aff|
// ---------------------------------------------------------------------------
__global__ __launch_bounds__(128) void conv_gen(const float* __restrict__ kx,
                                                const float* __restrict__ Wf,
                                                const float* __restrict__ bf,
                                                float* __restrict__ K)
{
    int tid = blockIdx.x * 128 + threadIdx.x;
    const int XT = WW / 8;              // 80 thread-columns
    int x8 = tid % XT;
    int t2 = tid / XT;
    int y  = t2 % HH;
    int b  = t2 / HH;
    if (b >= BB) return;
    int x0 = x8 * 8;

    float acc[8][8];
#pragma unroll
    for (int o = 0; o < 8; ++o) {
        float bv = bf[o];
#pragma unroll
        for (int p = 0; p < 8; ++p) acc[o][p] = bv;
    }

    const float* kxb = kx + (size_t)b * CC * HWv + (size_t)y * WW + x0;
    const bool xm = (x0 > 0);
    const bool xp = (x0 + 8 < WW);

    for (int c = 0; c < CC; ++c) {
        const float* pl = kxb + (size_t)c * HWv;
#pragma unroll
        for (int r = 0; r < 3; ++r) {
            const int dy = r - 1;
            const bool rowok = (y + dy >= 0) && (y + dy < HH);
            const float* rp = pl + dy * WW;
            float row[10];
            if (rowok) {
                float4 v0 = *reinterpret_cast<const float4*>(rp);
                float4 v1 = *reinterpret_cast<const float4*>(rp + 4);
                row[0] = xm ? rp[-1] : 0.f;
                row[1] = v0.x; row[2] = v0.y; row[3] = v0.z; row[4] = v0.w;
                row[5] = v1.x; row[6] = v1.y; row[7] = v1.z; row[8] = v1.w;
                row[9] = xp ? rp[8] : 0.f;
            } else {
#pragma unroll
                for (int q = 0; q < 10; ++q) row[q] = 0.f;
            }
#pragma unroll
            for (int o = 0; o < 8; ++o) {
#pragma unroll
                for (int t = 0; t < 3; ++t) {
                    // wave-uniform index -> s_load -> SGPR operand in v_fma
                    float wv = Wf[((o * CC + c) * 3 + r) * 3 + t];
#pragma unroll
                    for (int p = 0; p < 8; ++p) acc[o][p] += wv * row[p + t];
                }
            }
        }
    }

    // normalization: a = aff / sum|aff|; K0 = 1 - sum(a)
    float k0[8];
#pragma unroll
    for (int p = 0; p < 8; ++p) {
        float asum = 0.f;
#pragma unroll
        for (int o = 0; o < 8; ++o) asum += fabsf(acc[o][p]);
        float rinv = 1.0f / asum;
        float s = 0.f;
#pragma unroll
        for (int o = 0; o < 8; ++o) { acc[o][p] *= rinv; s += acc[o][p]; }
        k0[p] = 1.0f - s;
    }

    size_t base = (size_t)b * 9 * HWv + (size_t)y * WW + x0;
    *reinterpret_cast<float4*>(K + base)     = make_float4(k0[0], k0[1], k0[2], k0[3]);
    *reinterpret_cast<float4*>(K + base + 4) = make_float4(k0[4], k0[5], k0[6], k0[7]);
#pragma unroll
    for (int o = 0; o < 8; ++o) {
        size_t pb = base + (size_t)(o + 1) * HWv;
        *reinterpret_cast<float4*>(K + pb)     = make_float4(acc[o][0], acc[o][1], acc[o][2], acc[o][3]);
        *reinterpret_cast<float4*>(K + pb + 4) = make_float4(acc[o][4], acc[o][5], acc[o][6], acc[o][7]);
    }
}

// ---------------------------------------------------------------------------
// Kernel 2: FOUR fused propagation iterations per launch.
// Tile: 48x48 output, staged 56x56 x-region in LDS (ping-pong), redundant
// halo compute (regions 54^2 -> 52^2 -> 50^2 -> 48^2). K read per-step from
// global: block working set ~105 KB -> L2-resident for steps 2-4.
// OFFSETS order: (0,0),(0,1),(0,-1),(1,0),(1,1),(1,-1),(-1,0),(-1,1),(-1,-1)
//   out(r,c) = k0*x[r,c] + k1*x[r,c-1] + k2*x[r,c+1]
//            + k3*x[r-1,c] + k4*x[r-1,c-1] + k5*x[r-1,c+1]
//            + k6*x[r+1,c] + k7*x[r+1,c-1] + k8*x[r+1,c+1]
// Out-of-image positions forced to 0 after each step (zero-pad semantics).
// ---------------------------------------------------------------------------
#define PT 48
#define PS 56
#define PNX 14        // ceil(640/48) -> covers 672 cols, store-guarded
#define PNY 10        // 480/48

__global__ __launch_bounds__(256) void prop4(const float* __restrict__ xin,
                                             const float* __restrict__ Kk,
                                             float* __restrict__ xout)
{
    __shared__ float xs[2][PS * PS];    // 2 x 12.25 KB

    const int t  = threadIdx.x;
    const int c  = t & 63;              // 0..63 (active when c < PS)
    const int r0 = t >> 6;              // 0..3

    int blk = blockIdx.x;
    const int xt = blk % PNX; blk /= PNX;
    const int yt = blk % PNY;
    const int b  = blk / PNY;
    const int gx0 = xt * PT - 4;        // staged-region origin
    const int gy0 = yt * PT - 4;

    const float* xb = xin + (size_t)b * HWv;
    const float* Kb = Kk + (size_t)b * 9 * HWv;

    // ---- stage x (zero outside image) ----
    if (c < PS) {
#pragma unroll
        for (int r = r0; r < PS; r += 4) {
            int gy = gy0 + r, gx = gx0 + c;
            bool ok = (gy >= 0 && gy < HH && gx >= 0 && gx < WW);
            const float* src = xb + (size_t)(ok ? gy : 0) * WW + (ok ? gx : 0);
            xs[0][r * PS + c] = ok ? *src : 0.f;
        }
    }
    __syncthreads();

    // per-thread column constants
    int gxc  = gx0 + c;
    int gxcl = gxc < 0 ? 0 : (gxc > WW - 1 ? WW - 1 : gxc);
    const float mx = (gxc >= 0 && gxc < WW) ? 1.f : 0.f;

    int cur = 0;
#pragma unroll
    for (int s = 1; s <= 4; ++s) {
        int nxt = cur ^ 1;
        if (c < PS) {
#pragma unroll
            for (int r = r0; r < PS; r += 4) {
                if (r >= s && r < PS - s && c >= s && c < PS - s) {
                    int gy  = gy0 + r;
                    int gyl = gy < 0 ? 0 : (gy > HH - 1 ? HH - 1 : gy);
                    float m = ((gy >= 0 && gy < HH) ? 1.f : 0.f) * mx;
                    const float* kp = Kb + (size_t)gyl * WW + gxcl;
                    const float* xc = &xs[cur][r * PS + c];
                    float v = kp[0 * HWv] * xc[0]
                            + kp[1 * HWv] * xc[-1]
                            + kp[2 * HWv] * xc[1]
                            + kp[3 * HWv] * xc[-PS]
                            + kp[4 * HWv] * xc[-PS - 1]
                            + kp[5 * HWv] * xc[-PS + 1]
                            + kp[6 * HWv] * xc[PS]
                            + kp[7 * HWv] * xc[PS - 1]
                            + kp[8 * HWv] * xc[PS + 1];
                    xs[nxt][r * PS + c] = v * m;
                }
            }
        }
        __syncthreads();
        cur = nxt;
    }

    // ---- write margin-4 region (the 48x48 output tile) ----
    if (c >= 4 && c < 52) {
#pragma unroll
        for (int r = r0; r < PS; r += 4) {
            if (r >= 4 && r < 52) {
                int gy = gy0 + r, gx = gx0 + c;
                if (gx < WW)
                    xout[(size_t)b * HWv + (size_t)gy * WW + gx] = xs[cur][r * PS + c];
            }
        }
    }
}

// ---------------------------------------------------------------------------
extern "C" void kernel_launch(void* const* d_in, const int* in_sizes, int n_in,
                              void* d_out, int out_size, void* d_ws, size_t ws_size,
                              hipStream_t stream) {
    const float* kx   = (const float*)d_in[0];   // [4,32,480,640]
    const float* x_in = (const float*)d_in[1];   // [4,1,480,640]
    const float* Wf   = (const float*)d_in[2];   // [8,32,3,3]
    const float* bf   = (const float*)d_in[3];   // [8]
    float* out  = (float*)d_out;                 // [4,1,480,640]
    float* ws   = (float*)d_ws;

    float* Kbuf = ws;                             // 9*4*480*640 floats = 44.2 MB
    float* xbuf = ws + (size_t)9 * BB * HWv;      // 4*480*640 floats  =  4.9 MB

    // conv: 8 px/thread, block=128 -> 1200 blocks (R2 structure)
    const int cthreads = BB * HH * (WW / 8);      // 153600
    conv_gen<<<cthreads / 128, 128, 0, stream>>>(kx, Wf, bf, Kbuf);

    // prop: 3 launches x 4 fused iterations, 560 blocks x 256 threads
    const int pblocks = BB * PNY * PNX;           // 560
    prop4<<<pblocks, 256, 0, stream>>>(x_in, Kbuf, out);   // iters 1-4 (out = scratch)
    prop4<<<pblocks, 256, 0, stream>>>(out, Kbuf, xbuf);   // iters 5-8
    prop4<<<pblocks, 256, 0, stream>>>(xbuf, Kbuf, out);   // iters 9-12 -> final
}

// Round 8
// 247.394 us; speedup vs baseline: 1.0208x; 1.0208x over previous
//
#include <hip/hip_runtime.h>

#define BB 4
#define CC 32
#define HH 480
#define WW 640
#define HWv (HH*WW)

// ---------------------------------------------------------------------------
// Kernel 1: 3x3 conv (32->8) + bias + affinity normalization, fused.
// R2 structure (best measured: 115.5 us) + ONE change: the 2304 weights are
// staged into LDS once per block and read in the FMA loop as wave-uniform
// broadcast ds_reads (2x b128 + 1x b32 per (o,c), 48B-padded rows), instead
// of per-thread global loads. If the weight reads were previously VMEM
// (not s_load), this removes 2304 VMEM ops from the inner loop.
// Output: K [B][9][H][W], K[0] = 1 - sum(a), K[1..8] = a_k = aff_k / sum|aff|
// ---------------------------------------------------------------------------
__global__ __launch_bounds__(128) void conv_gen(const float* __restrict__ kx,
                                                const float* __restrict__ Wf,
                                                const float* __restrict__ bf,
                                                float* __restrict__ K)
{
    __shared__ float wl[8 * CC * 12];   // 12288 B, (o,c) rows padded 9->12

    // one-time weight staging (all threads, coalesced)
    for (int i = threadIdx.x; i < 8 * CC * 9; i += 128) {
        int oc = i / 9, k = i - oc * 9;
        wl[oc * 12 + k] = Wf[i];
    }
    __syncthreads();

    int tid = blockIdx.x * 128 + threadIdx.x;
    const int XT = WW / 8;              // 80 thread-columns
    int x8 = tid % XT;
    int t2 = tid / XT;
    int y  = t2 % HH;
    int b  = t2 / HH;
    if (b >= BB) return;
    int x0 = x8 * 8;

    float acc[8][8];
#pragma unroll
    for (int o = 0; o < 8; ++o) {
        float bv = bf[o];
#pragma unroll
        for (int p = 0; p < 8; ++p) acc[o][p] = bv;
    }

    const float* kxb = kx + (size_t)b * CC * HWv + (size_t)y * WW + x0;
    const bool xm = (x0 > 0);
    const bool xp = (x0 + 8 < WW);

    for (int c = 0; c < CC; ++c) {
        const float* pl = kxb + (size_t)c * HWv;
        float row3[3][10];
#pragma unroll
        for (int r = 0; r < 3; ++r) {
            const int dy = r - 1;
            const bool rowok = (y + dy >= 0) && (y + dy < HH);
            const float* rp = pl + dy * WW;
            if (rowok) {
                float4 v0 = *reinterpret_cast<const float4*>(rp);
                float4 v1 = *reinterpret_cast<const float4*>(rp + 4);
                row3[r][0] = xm ? rp[-1] : 0.f;
                row3[r][1] = v0.x; row3[r][2] = v0.y; row3[r][3] = v0.z; row3[r][4] = v0.w;
                row3[r][5] = v1.x; row3[r][6] = v1.y; row3[r][7] = v1.z; row3[r][8] = v1.w;
                row3[r][9] = xp ? rp[8] : 0.f;
            } else {
#pragma unroll
                for (int q = 0; q < 10; ++q) row3[r][q] = 0.f;
            }
        }

#pragma unroll
        for (int o = 0; o < 8; ++o) {
            // 9 weights for (o,c): wave-uniform LDS broadcast, aligned
            const float* wp = &wl[(o * CC + c) * 12];
            float4 wa = *reinterpret_cast<const float4*>(wp);      // w0..w3
            float4 wb = *reinterpret_cast<const float4*>(wp + 4);  // w4..w7
            float  w8 = wp[8];
            float w[9] = {wa.x, wa.y, wa.z, wa.w, wb.x, wb.y, wb.z, wb.w, w8};
#pragma unroll
            for (int r = 0; r < 3; ++r) {
#pragma unroll
                for (int t = 0; t < 3; ++t) {
                    float wv = w[r * 3 + t];
#pragma unroll
                    for (int p = 0; p < 8; ++p) acc[o][p] += wv * row3[r][p + t];
                }
            }
        }
    }

    // normalization: a = aff / sum|aff|; K0 = 1 - sum(a)
    float k0[8];
#pragma unroll
    for (int p = 0; p < 8; ++p) {
        float asum = 0.f;
#pragma unroll
        for (int o = 0; o < 8; ++o) asum += fabsf(acc[o][p]);
        float rinv = 1.0f / asum;
        float s = 0.f;
#pragma unroll
        for (int o = 0; o < 8; ++o) { acc[o][p] *= rinv; s += acc[o][p]; }
        k0[p] = 1.0f - s;
    }

    size_t base = (size_t)b * 9 * HWv + (size_t)y * WW + x0;
    *reinterpret_cast<float4*>(K + base)     = make_float4(k0[0], k0[1], k0[2], k0[3]);
    *reinterpret_cast<float4*>(K + base + 4) = make_float4(k0[4], k0[5], k0[6], k0[7]);
#pragma unroll
    for (int o = 0; o < 8; ++o) {
        size_t pb = base + (size_t)(o + 1) * HWv;
        *reinterpret_cast<float4*>(K + pb)     = make_float4(acc[o][0], acc[o][1], acc[o][2], acc[o][3]);
        *reinterpret_cast<float4*>(K + pb + 4) = make_float4(acc[o][4], acc[o][5], acc[o][6], acc[o][7]);
    }
}

// ---------------------------------------------------------------------------
// Kernel 2: one propagation iteration (R1 structure — proven 7.3 us/launch).
// OFFSETS order: (0,0),(0,1),(0,-1),(1,0),(1,1),(1,-1),(-1,0),(-1,1),(-1,-1)
// ---------------------------------------------------------------------------
__device__ __forceinline__ void load_row6(const float* r, bool rowok, bool xm,
                                          bool xpl, float o[6])
{
    if (rowok) {
        float4 v = *reinterpret_cast<const float4*>(r);
        o[0] = xm ? r[-1] : 0.f;
        o[1] = v.x; o[2] = v.y; o[3] = v.z; o[4] = v.w;
        o[5] = xpl ? r[4] : 0.f;
    } else {
#pragma unroll
        for (int q = 0; q < 6; ++q) o[q] = 0.f;
    }
}

__global__ __launch_bounds__(256) void prop(const float* __restrict__ xin,
                                            const float* __restrict__ K,
                                            float* __restrict__ xout)
{
    int tid = blockIdx.x * 256 + threadIdx.x;
    const int XT = WW / 4;
    int x4 = tid % XT;
    int t2 = tid / XT;
    int y  = t2 % HH;
    int b  = t2 / HH;
    if (b >= BB) return;
    int x0 = x4 * 4;

    const bool xm  = (x0 > 0);
    const bool xpl = (x0 + 4 < WW);

    const float* xb = xin + (size_t)b * HWv + (size_t)y * WW + x0;
    float rm[6], r0[6], rp[6];
    load_row6(xb - WW, y > 0,      xm, xpl, rm);
    load_row6(xb,      true,       xm, xpl, r0);
    load_row6(xb + WW, y < HH - 1, xm, xpl, rp);

    const float* Kb = K + (size_t)b * 9 * HWv + (size_t)y * WW + x0;
    float kv[9][4];
#pragma unroll
    for (int k = 0; k < 9; ++k) {
        float4 v = *reinterpret_cast<const float4*>(Kb + (size_t)k * HWv);
        kv[k][0] = v.x; kv[k][1] = v.y; kv[k][2] = v.z; kv[k][3] = v.w;
    }

    float out[4];
#pragma unroll
    for (int p = 0; p < 4; ++p) {
        out[p] = kv[0][p] * r0[p + 1]
               + kv[1][p] * r0[p]
               + kv[2][p] * r0[p + 2]
               + kv[3][p] * rm[p + 1]
               + kv[4][p] * rm[p]
               + kv[5][p] * rm[p + 2]
               + kv[6][p] * rp[p + 1]
               + kv[7][p] * rp[p]
               + kv[8][p] * rp[p + 2];
    }

    *reinterpret_cast<float4*>(xout + (size_t)b * HWv + (size_t)y * WW + x0) =
        make_float4(out[0], out[1], out[2], out[3]);
}

// ---------------------------------------------------------------------------
extern "C" void kernel_launch(void* const* d_in, const int* in_sizes, int n_in,
                              void* d_out, int out_size, void* d_ws, size_t ws_size,
                              hipStream_t stream) {
    const float* kx   = (const float*)d_in[0];   // [4,32,480,640]
    const float* x_in = (const float*)d_in[1];   // [4,1,480,640]
    const float* Wf   = (const float*)d_in[2];   // [8,32,3,3]
    const float* bf   = (const float*)d_in[3];   // [8]
    float* out  = (float*)d_out;                 // [4,1,480,640]
    float* ws   = (float*)d_ws;

    float* Kbuf = ws;                             // 9*4*480*640 floats = 44.2 MB
    float* xbuf = ws + (size_t)9 * BB * HWv;      // 4*480*640 floats  =  4.9 MB

    // conv: 8 px/thread, block=128 -> 1200 blocks
    const int cthreads = BB * HH * (WW / 8);      // 153600
    conv_gen<<<cthreads / 128, 128, 0, stream>>>(kx, Wf, bf, Kbuf);

    // prop: 4 px/thread, block=256 -> 1200 blocks, 12 launches
    const int pthreads = BB * HH * (WW / 4);      // 307200
    const int pblocks  = pthreads / 256;          // 1200

    const float* src = x_in;
    for (int it = 0; it < 12; ++it) {
        float* dst = (it % 2 == 0) ? xbuf : out;  // it=11 (odd) -> d_out
        prop<<<pblocks, 256, 0, stream>>>(src, Kbuf, dst);
        src = dst;
    }
}

// Round 9
// 170.735 us; speedup vs baseline: 1.4791x; 1.4490x over previous
//
#include <hip/hip_runtime.h>
#include <hip/hip_fp16.h>

#define BB 4
#define CC 32
#define HH 480
#define WW 640
#define HWv (HH*WW)

// ---------------------------------------------------------------------------
// Kernel 1: 3x3 conv (32->8) + bias + affinity normalization, fused.
// Exact R2 compute structure (best measured: 115.5 us). Only change: the
// normalized kernel K is stored as FP16 (values bounded: a in [-1,1],
// k0 in [0,2]; f32 math throughout, RTN convert at store). Halves K traffic
// for all 12 propagation iterations.
// Output: K [B][9][H][W] fp16, K[0] = 1 - sum(a), K[1..8] = aff_k / sum|aff|
// ---------------------------------------------------------------------------
union H8 { __half h[8]; float4 f4; };

__global__ __launch_bounds__(128) void conv_gen(const float* __restrict__ kx,
                                                const float* __restrict__ Wf,
                                                const float* __restrict__ bf,
                                                __half* __restrict__ K)
{
    int tid = blockIdx.x * 128 + threadIdx.x;
    const int XT = WW / 8;              // 80 thread-columns
    int x8 = tid % XT;
    int t2 = tid / XT;
    int y  = t2 % HH;
    int b  = t2 / HH;
    if (b >= BB) return;
    int x0 = x8 * 8;

    float acc[8][8];
#pragma unroll
    for (int o = 0; o < 8; ++o) {
        float bv = bf[o];
#pragma unroll
        for (int p = 0; p < 8; ++p) acc[o][p] = bv;
    }

    const float* kxb = kx + (size_t)b * CC * HWv + (size_t)y * WW + x0;
    const bool xm = (x0 > 0);
    const bool xp = (x0 + 8 < WW);

    for (int c = 0; c < CC; ++c) {
        const float* pl = kxb + (size_t)c * HWv;
#pragma unroll
        for (int r = 0; r < 3; ++r) {
            const int dy = r - 1;
            const bool rowok = (y + dy >= 0) && (y + dy < HH);
            const float* rp = pl + dy * WW;
            float row[10];
            if (rowok) {
                float4 v0 = *reinterpret_cast<const float4*>(rp);
                float4 v1 = *reinterpret_cast<const float4*>(rp + 4);
                row[0] = xm ? rp[-1] : 0.f;
                row[1] = v0.x; row[2] = v0.y; row[3] = v0.z; row[4] = v0.w;
                row[5] = v1.x; row[6] = v1.y; row[7] = v1.z; row[8] = v1.w;
                row[9] = xp ? rp[8] : 0.f;
            } else {
#pragma unroll
                for (int q = 0; q < 10; ++q) row[q] = 0.f;
            }
#pragma unroll
            for (int o = 0; o < 8; ++o) {
#pragma unroll
                for (int t = 0; t < 3; ++t) {
                    // wave-uniform index -> s_load -> SGPR operand in v_fma
                    float wv = Wf[((o * CC + c) * 3 + r) * 3 + t];
#pragma unroll
                    for (int p = 0; p < 8; ++p) acc[o][p] += wv * row[p + t];
                }
            }
        }
    }

    // normalization: a = aff / sum|aff|; K0 = 1 - sum(a)
    float k0[8];
#pragma unroll
    for (int p = 0; p < 8; ++p) {
        float asum = 0.f;
#pragma unroll
        for (int o = 0; o < 8; ++o) asum += fabsf(acc[o][p]);
        float rinv = 1.0f / asum;
        float s = 0.f;
#pragma unroll
        for (int o = 0; o < 8; ++o) { acc[o][p] *= rinv; s += acc[o][p]; }
        k0[p] = 1.0f - s;
    }

    size_t base = (size_t)b * 9 * HWv + (size_t)y * WW + x0;   // element idx
    {
        H8 u;
#pragma unroll
        for (int p = 0; p < 8; ++p) u.h[p] = __float2half(k0[p]);
        *reinterpret_cast<float4*>(K + base) = u.f4;            // 16 B store
    }
#pragma unroll
    for (int o = 0; o < 8; ++o) {
        H8 u;
#pragma unroll
        for (int p = 0; p < 8; ++p) u.h[p] = __float2half(acc[o][p]);
        *reinterpret_cast<float4*>(K + base + (size_t)(o + 1) * HWv) = u.f4;
    }
}

// ---------------------------------------------------------------------------
// Kernel 2: one propagation iteration (R1 structure, K now fp16).
// OFFSETS order: (0,0),(0,1),(0,-1),(1,0),(1,1),(1,-1),(-1,0),(-1,1),(-1,-1)
// ---------------------------------------------------------------------------
__device__ __forceinline__ void load_row6(const float* r, bool rowok, bool xm,
                                          bool xpl, float o[6])
{
    if (rowok) {
        float4 v = *reinterpret_cast<const float4*>(r);
        o[0] = xm ? r[-1] : 0.f;
        o[1] = v.x; o[2] = v.y; o[3] = v.z; o[4] = v.w;
        o[5] = xpl ? r[4] : 0.f;
    } else {
#pragma unroll
        for (int q = 0; q < 6; ++q) o[q] = 0.f;
    }
}

union H4 { short4 s; __half h[4]; };

__global__ __launch_bounds__(256) void prop(const float* __restrict__ xin,
                                            const __half* __restrict__ K,
                                            float* __restrict__ xout)
{
    int tid = blockIdx.x * 256 + threadIdx.x;
    const int XT = WW / 4;
    int x4 = tid % XT;
    int t2 = tid / XT;
    int y  = t2 % HH;
    int b  = t2 / HH;
    if (b >= BB) return;
    int x0 = x4 * 4;

    const bool xm  = (x0 > 0);
    const bool xpl = (x0 + 4 < WW);

    const float* xb = xin + (size_t)b * HWv + (size_t)y * WW + x0;
    float rm[6], r0[6], rp[6];
    load_row6(xb - WW, y > 0,      xm, xpl, rm);
    load_row6(xb,      true,       xm, xpl, r0);
    load_row6(xb + WW, y < HH - 1, xm, xpl, rp);

    const __half* Kb = K + (size_t)b * 9 * HWv + (size_t)y * WW + x0;
    float kv[9][4];
#pragma unroll
    for (int k = 0; k < 9; ++k) {
        H4 u;
        u.s = *reinterpret_cast<const short4*>(Kb + (size_t)k * HWv);  // 8 B
#pragma unroll
        for (int p = 0; p < 4; ++p) kv[k][p] = __half2float(u.h[p]);
    }

    float out[4];
#pragma unroll
    for (int p = 0; p < 4; ++p) {
        out[p] = kv[0][p] * r0[p + 1]
               + kv[1][p] * r0[p]
               + kv[2][p] * r0[p + 2]
               + kv[3][p] * rm[p + 1]
               + kv[4][p] * rm[p]
               + kv[5][p] * rm[p + 2]
               + kv[6][p] * rp[p + 1]
               + kv[7][p] * rp[p]
               + kv[8][p] * rp[p + 2];
    }

    *reinterpret_cast<float4*>(xout + (size_t)b * HWv + (size_t)y * WW + x0) =
        make_float4(out[0], out[1], out[2], out[3]);
}

// ---------------------------------------------------------------------------
extern "C" void kernel_launch(void* const* d_in, const int* in_sizes, int n_in,
                              void* d_out, int out_size, void* d_ws, size_t ws_size,
                              hipStream_t stream) {
    const float* kx   = (const float*)d_in[0];   // [4,32,480,640]
    const float* x_in = (const float*)d_in[1];   // [4,1,480,640]
    const float* Wf   = (const float*)d_in[2];   // [8,32,3,3]
    const float* bf   = (const float*)d_in[3];   // [8]
    float* out  = (float*)d_out;                 // [4,1,480,640]

    __half* Kbuf = (__half*)d_ws;                               // 22.1 MB fp16
    float*  xbuf = (float*)((char*)d_ws +
                            (size_t)9 * BB * HWv * sizeof(__half));  // 4.9 MB

    // conv: 8 px/thread, block=128 -> 1200 blocks (R2 structure)
    const int cthreads = BB * HH * (WW / 8);      // 153600
    conv_gen<<<cthreads / 128, 128, 0, stream>>>(kx, Wf, bf, Kbuf);

    // prop: 4 px/thread, block=256 -> 1200 blocks, 12 launches
    const int pthreads = BB * HH * (WW / 4);      // 307200
    const int pblocks  = pthreads / 256;          // 1200

    const float* src = x_in;
    for (int it = 0; it < 12; ++it) {
        float* dst = (it % 2 == 0) ? xbuf : out;  // it=11 (odd) -> d_out
        prop<<<pblocks, 256, 0, stream>>>(src, Kbuf, dst);
        src = dst;
    }
}